// Round 1
// baseline (197.469 us; speedup 1.0000x reference)
//
#include <hip/hip_runtime.h>

// HingeAUCLoss: loss = (1/(E(E-1))) * sum_{i,j: t[i]!=t[j]} relu(1 - f_own[j] + pred[i,t[j]]) / (N[t[i]] N[t[j]])
// Decomposition: per-slot j: {thr = f_own[j]-1, wv = 1/N[t[j]], col = t[j]}.
// Row i accumulates sum_j relu(pred[i,col] - thr)*wv*(col!=t[i]), then * 1/N[t[i]].

#define C_CLASSES 1000
#define ROWS 16       // pred rows staged in LDS per block
#define GROUPS 16     // slot interleave groups (ROWS*GROUPS = 256 threads)
#define TPB 256
#define LDS_STRIDE 1004  // floats; 1004/4=251, 251%32=27 (odd) -> column gather conflict-free; 16B aligned

__global__ void k_init(int* ncnt, float* scal) {
    int t = blockIdx.x * blockDim.x + threadIdx.x;
    if (t < 1024) ncnt[t] = 0;
    if (t < 8) scal[t] = 0.f;
}

__global__ void k_hist(const int* __restrict__ target, int* ncnt, int B) {
    int j = blockIdx.x * blockDim.x + threadIdx.x;
    if (j < B) atomicAdd(&ncnt[target[j]], 1);
}

__global__ void k_invn(const int* __restrict__ ncnt, float* invN, float* scal) {
    int c = threadIdx.x;
    int n = 0;
    if (c < C_CLASSES) {
        n = ncnt[c];
        invN[c] = (n > 0) ? 1.0f / (float)n : 0.f;
    }
    unsigned long long m = __ballot(n > 0);
    __shared__ int es;
    if (threadIdx.x == 0) es = 0;
    __syncthreads();
    if ((threadIdx.x & 63) == 0) atomicAdd(&es, __popcll(m));
    __syncthreads();
    if (threadIdx.x == 0) scal[0] = (float)es;  // E
}

__global__ void k_slots(const float* __restrict__ pred, const int* __restrict__ target,
                        const float* __restrict__ invN, float4* __restrict__ slots, int B) {
    int j = blockIdx.x * blockDim.x + threadIdx.x;
    if (j >= B) return;
    int tj = target[j];
    float fo = pred[(size_t)j * C_CLASSES + tj];  // f_own[j]
    slots[j] = make_float4(fo - 1.0f, invN[tj], __int_as_float(tj), 0.f);
}

__global__ __launch_bounds__(TPB) void k_main(const float* __restrict__ pred,
                                              const int* __restrict__ target,
                                              const float4* __restrict__ slots,
                                              const float* __restrict__ invN,
                                              float* scal, int B) {
    __shared__ float predL[ROWS][LDS_STRIDE];
    __shared__ float red[TPB / 64];
    const int tid = threadIdx.x;
    const int i0 = blockIdx.x * ROWS;

    // Stage ROWS rows of pred into LDS, coalesced float4 loads.
    for (int idx = tid; idx < ROWS * (C_CLASSES / 4); idx += TPB) {
        int r = idx / (C_CLASSES / 4);
        int q = idx % (C_CLASSES / 4);
        if (i0 + r < B) {
            float4 v = reinterpret_cast<const float4*>(pred + (size_t)(i0 + r) * C_CLASSES)[q];
            *reinterpret_cast<float4*>(&predL[r][q * 4]) = v;
        }
    }
    __syncthreads();

    const int r = tid & (ROWS - 1);   // row within tile
    const int g = tid >> 4;           // slot group 0..15
    const bool valid = (i0 + r) < B;
    const int ti = valid ? target[i0 + r] : 0;
    const float w_i = valid ? invN[ti] : 0.f;

    float a0 = 0.f, a1 = 0.f;
    if (valid) {
        int s = g;
        // two-slot steps, interleaved groups -> wave's 4 groups load 4 consecutive
        // float4 slots (64B coalesced, L2-resident)
        for (; s + GROUPS < B; s += 2 * GROUPS) {
            float4 sl0 = slots[s];
            float4 sl1 = slots[s + GROUPS];
            int c0 = __float_as_int(sl0.z);
            int c1 = __float_as_int(sl1.z);
            float p0 = predL[r][c0];
            float p1 = predL[r][c1];
            float d0 = fmaxf(p0 - sl0.x, 0.f);
            float d1 = fmaxf(p1 - sl1.x, 0.f);
            float wv0 = (c0 == ti) ? 0.f : sl0.y;
            float wv1 = (c1 == ti) ? 0.f : sl1.y;
            a0 = fmaf(d0, wv0, a0);
            a1 = fmaf(d1, wv1, a1);
        }
        for (; s < B; s += GROUPS) {
            float4 sl = slots[s];
            int c = __float_as_int(sl.z);
            float p = predL[r][c];
            float d = fmaxf(p - sl.x, 0.f);
            float wv = (c == ti) ? 0.f : sl.y;
            a0 = fmaf(d, wv, a0);
        }
    }

    float a = (a0 + a1) * w_i;
    // wave64 reduce
    for (int off = 32; off > 0; off >>= 1) a += __shfl_down(a, off);
    if ((tid & 63) == 0) red[tid >> 6] = a;
    __syncthreads();
    if (tid == 0) atomicAdd(&scal[1], red[0] + red[1] + red[2] + red[3]);
}

__global__ void k_final(const float* __restrict__ scal, float* __restrict__ out) {
    float E = scal[0];
    out[0] = scal[1] / (E * (E - 1.0f));
}

extern "C" void kernel_launch(void* const* d_in, const int* in_sizes, int n_in,
                              void* d_out, int out_size, void* d_ws, size_t ws_size,
                              hipStream_t stream) {
    const float* pred = (const float*)d_in[0];
    const int* target = (const int*)d_in[1];
    const int B = in_sizes[1];  // 12288

    char* ws = (char*)d_ws;
    int* ncnt = (int*)ws;                        // 1024 ints
    float* invN = (float*)(ws + 4096);           // 1024 floats
    float* scal = (float*)(ws + 8192);           // [0]=E, [1]=acc
    float4* slots = (float4*)(ws + 8448);        // B float4s (~196KB)

    const int gb = (B + 255) / 256;
    const int gmain = (B + ROWS - 1) / ROWS;

    k_init<<<4, 256, 0, stream>>>(ncnt, scal);
    k_hist<<<gb, 256, 0, stream>>>(target, ncnt, B);
    k_invn<<<1, 1024, 0, stream>>>(ncnt, invN, scal);
    k_slots<<<gb, 256, 0, stream>>>(pred, target, invN, slots, B);
    k_main<<<gmain, TPB, 0, stream>>>(pred, target, slots, invN, scal, B);
    k_final<<<1, 1, 0, stream>>>(scal, (float*)d_out);
}

// Round 2
// 98.930 us; speedup vs baseline: 1.9961x; 1.9961x over previous
//
#include <hip/hip_runtime.h>
#include <float.h>

// loss = (1/(E(E-1))) * sum_{i,j: t_i != t_j} relu(pred[i,t_j] - (f_own[j]-1)) / (N[t_i] N[t_j])
// Per class c: sorted thresholds thr + prefix sums -> row contribution = (k*p - prefix[k]) / N[c]
// where k = #{thr < p}, p = pred[i,c]. Work: O(B*C*log) instead of O(B^2).

#define CCLS 1000
#define TPB 1024
#define CCH 256       // classes per chunk
#define CAP 4608      // LDS slot capacity per chunk (expected ~3400, 22-sigma safe; global fallback kept)
#define NCCHUNK 4
#define NRBLK 128

__global__ void k_init(int* ncnt, int* fill, float* scal) {
    int t = blockIdx.x * 256 + threadIdx.x;
    if (t < 1024) { ncnt[t] = 0; fill[t] = 0; }
    if (t < 16) scal[t] = 0.f;
}

__global__ void k_hist(const int* __restrict__ target, int* ncnt, int B) {
    int j = blockIdx.x * 256 + threadIdx.x;
    if (j < B) atomicAdd(&ncnt[target[j]], 1);
}

// E, invN, and exclusive scan of (N[c]+1) -> segment offsets (each class gets cnt+1 slots, +1 = sentinel)
__global__ __launch_bounds__(1024) void k_scan(const int* __restrict__ ncnt,
                                               float* invN, int* off, float* scal) {
    __shared__ int s[1024];
    __shared__ int esh;
    int tid = threadIdx.x;
    if (tid == 0) esh = 0;
    int n = (tid < CCLS) ? ncnt[tid] : 0;
    __syncthreads();
    unsigned long long m = __ballot(n > 0);
    if ((tid & 63) == 0) atomicAdd(&esh, __popcll(m));
    if (tid < CCLS) invN[tid] = (n > 0) ? 1.0f / (float)n : 0.f;
    int v = (tid < CCLS) ? (n + 1) : 0;
    s[tid] = v;
    __syncthreads();
    for (int d = 1; d < 1024; d <<= 1) {
        int add = (tid >= d) ? s[tid - d] : 0;
        __syncthreads();
        s[tid] += add;
        __syncthreads();
    }
    if (tid < CCLS) off[tid] = s[tid] - v;
    if (tid == CCLS - 1) off[CCLS] = s[tid];
    if (tid == 0) scal[0] = (float)esh;
}

__global__ void k_scatter(const float* __restrict__ pred, const int* __restrict__ target,
                          const int* __restrict__ off, int* fill, float* thr_g, int B) {
    int j = blockIdx.x * 256 + threadIdx.x;
    if (j >= B) return;
    int tj = target[j];
    float fo = pred[(size_t)j * CCLS + tj];
    int pos = off[tj] + atomicAdd(&fill[tj], 1);
    thr_g[pos] = fo - 1.0f;
}

// per-class insertion sort (counts ~12) + prefix sums + FLT_MAX sentinel
__global__ void k_sortpfx(const int* __restrict__ ncnt, const int* __restrict__ off,
                          float* thr_g, float* pref_g) {
    int c = blockIdx.x * 256 + threadIdx.x;
    if (c >= CCLS) return;
    int base = off[c], cnt = ncnt[c];
    for (int a = 1; a < cnt; ++a) {
        float v = thr_g[base + a];
        int b = a - 1;
        while (b >= 0 && thr_g[base + b] > v) { thr_g[base + b + 1] = thr_g[base + b]; --b; }
        thr_g[base + b + 1] = v;
    }
    float run = 0.f;
    for (int k = 0; k < cnt; ++k) { pref_g[base + k] = run; run += thr_g[base + k]; }
    thr_g[base + cnt] = FLT_MAX;
    pref_g[base + cnt] = run;
}

__global__ __launch_bounds__(TPB) void k_main(const float* __restrict__ pred,
        const int* __restrict__ target,
        const float* __restrict__ thr_g, const float* __restrict__ pref_g,
        const int* __restrict__ off_g, const float* __restrict__ invN_g,
        float* scal, int B, int RPB) {
    __shared__ float thrL[CAP];
    __shared__ float prefL[CAP];
    __shared__ int offL[CCLS + 1];
    __shared__ float invNL[CCLS];
    __shared__ float redL[TPB / 64];

    const int tid = threadIdx.x;
    const int cchunk = blockIdx.x >> 7;          // 0..3
    const int rblk = blockIdx.x & (NRBLK - 1);   // 0..127
    const int c0 = cchunk * CCH;
    const int c1 = min(c0 + CCH, CCLS);
    const int rbase = rblk * RPB;

    for (int k = tid; k <= CCLS; k += TPB) offL[k] = off_g[k];
    for (int k = tid; k < CCLS; k += TPB) invNL[k] = invN_g[k];
    __syncthreads();
    const int sbase = offL[c0];
    const int nsl = offL[c1] - sbase;
    const bool fits = (nsl <= CAP);
    if (fits) {
        for (int k = tid; k < nsl; k += TPB) {
            thrL[k] = thr_g[sbase + k];
            prefL[k] = pref_g[sbase + k];
        }
    }
    __syncthreads();

    const int rr = tid >> 8;          // 0..3: row within 4-row group
    const int cc = tid & (CCH - 1);   // class within chunk
    const int c = c0 + cc;
    const bool cvalid = (c < c1);
    const int cload = cvalid ? c : c0;
    const float invc = cvalid ? invNL[c] : 0.f;
    const int segb = cvalid ? (offL[c] - sbase) : 0;
    const int cnt = cvalid ? (offL[c + 1] - offL[c] - 1) : 0;

    auto body = [&](const auto* thrP, const auto* prefP) -> float {
        // class is loop-invariant per thread: preload 3 binary-search levels into registers.
        // lower_bound invariant makes probes on a converged/empty range harmless
        // (they read an element >= p or the FLT_MAX sentinel).
        const int m1 = cnt >> 1;
        const int m2A = (m1 + 1 + cnt) >> 1, m2B = m1 >> 1;
        const int i3AA = (m2A + 1 + cnt) >> 1, i3AB = (m1 + 1 + m2A) >> 1;
        const int i3BA = (m2B + 1 + m1) >> 1,  i3BB = m2B >> 1;
        const float t1  = thrP[segb + m1];
        const float t2A = thrP[segb + m2A], t2B = thrP[segb + m2B];
        const float t3AA = thrP[segb + i3AA], t3AB = thrP[segb + i3AB];
        const float t3BA = thrP[segb + i3BA], t3BB = thrP[segb + i3BB];

        float acc = 0.f;
        for (int it = 0; it * 4 + rr < RPB; ++it) {
            const int i = rbase + it * 4 + rr;
            if (i >= B) break;
            const int ti = target[i];
            const float p = pred[(size_t)i * CCLS + cload];

            bool b1 = t1 < p;
            int lo = b1 ? m1 + 1 : 0;
            int hi = b1 ? cnt : m1;
            float t2  = b1 ? t2A : t2B;
            float t3h = b1 ? t3AA : t3BA;
            float t3l = b1 ? t3AB : t3BB;

            bool b2 = t2 < p;
            int m2 = (lo + hi) >> 1;
            lo = b2 ? m2 + 1 : lo;
            hi = b2 ? hi : m2;
            float t3 = b2 ? t3h : t3l;

            bool b3 = t3 < p;
            int m3 = (lo + hi) >> 1;
            lo = b3 ? m3 + 1 : lo;
            hi = b3 ? hi : m3;

            while (lo < hi) {
                int mid = (lo + hi) >> 1;
                bool bt = thrP[segb + mid] < p;
                lo = bt ? mid + 1 : lo;
                hi = bt ? hi : mid;
            }
            float contrib = (float)lo * p - prefP[segb + lo];
            float w = (c != ti) ? invc * invNL[ti] : 0.f;
            acc = fmaf(contrib, w, acc);
        }
        return acc;
    };

    float acc = fits ? body((const float*)thrL, (const float*)prefL)
                     : body(thr_g + sbase, pref_g + sbase);

    for (int o = 32; o; o >>= 1) acc += __shfl_down(acc, o);
    if ((tid & 63) == 0) redL[tid >> 6] = acc;
    __syncthreads();
    if (tid == 0) {
        float ssum = 0.f;
        for (int k = 0; k < TPB / 64; ++k) ssum += redL[k];
        atomicAdd(&scal[1], ssum);
    }
}

__global__ void k_final(const float* __restrict__ scal, float* __restrict__ out) {
    float E = scal[0];
    out[0] = scal[1] / (E * (E - 1.0f));
}

extern "C" void kernel_launch(void* const* d_in, const int* in_sizes, int n_in,
                              void* d_out, int out_size, void* d_ws, size_t ws_size,
                              hipStream_t stream) {
    const float* pred = (const float*)d_in[0];
    const int* target = (const int*)d_in[1];
    const int B = in_sizes[1];  // 12288

    char* ws = (char*)d_ws;
    int* ncnt   = (int*)(ws + 0);        // 1024 ints
    int* fill   = (int*)(ws + 4096);     // 1024 ints
    int* off    = (int*)(ws + 8192);     // 1001 ints
    float* invN = (float*)(ws + 16384);  // 1000 floats
    float* scal = (float*)(ws + 20480);  // [0]=E, [1]=acc
    size_t slotBytes = (size_t)(B + CCLS + 64) * sizeof(float);
    float* thr_g  = (float*)(ws + 24576);
    float* pref_g = (float*)(ws + 24576 + slotBytes);

    const int gb = (B + 255) / 256;
    const int RPB = (B + NRBLK - 1) / NRBLK;

    k_init<<<4, 256, 0, stream>>>(ncnt, fill, scal);
    k_hist<<<gb, 256, 0, stream>>>(target, ncnt, B);
    k_scan<<<1, 1024, 0, stream>>>(ncnt, invN, off, scal);
    k_scatter<<<gb, 256, 0, stream>>>(pred, target, off, fill, thr_g, B);
    k_sortpfx<<<4, 256, 0, stream>>>(ncnt, off, thr_g, pref_g);
    k_main<<<NCCHUNK * NRBLK, TPB, 0, stream>>>(pred, target, thr_g, pref_g, off, invN, scal, B, RPB);
    k_final<<<1, 1, 0, stream>>>(scal, (float*)d_out);
}

// Round 3
// 51.812 us; speedup vs baseline: 3.8113x; 1.9094x over previous
//
#include <hip/hip_runtime.h>
#include <float.h>

// loss = (1/(E(E-1))) * sum_{i,j: t_i != t_j} relu(pred[i,t_j] - (f_own[j]-1)) / (N[t_i] N[t_j])
// Per class c: sorted thresholds thr + prefix sums -> row contribution = (k*p - prefix[k]) / N[c]
// where k = #{thr < p}, p = pred[i,c]. Work: O(B*C*log) instead of O(B^2).

#define CCLS 1000
#define TPB 1024
#define CCH 256       // classes per chunk
#define CAP 4608      // LDS slot capacity per chunk (expected ~3400, 22-sigma safe; global fallback kept)
#define NCCHUNK 4
#define NRBLK 128

__global__ void k_init(int* ncnt, int* fill, float* scal) {
    int t = blockIdx.x * 256 + threadIdx.x;
    if (t < 1024) { ncnt[t] = 0; fill[t] = 0; }
    if (t < 16) scal[t] = 0.f;
}

__global__ void k_hist(const int* __restrict__ target, int* ncnt, int B) {
    int j = blockIdx.x * 256 + threadIdx.x;
    if (j < B) atomicAdd(&ncnt[target[j]], 1);
}

// E, invN, and exclusive scan of (N[c]+1) -> segment offsets (each class gets cnt+1 slots, +1 = sentinel)
__global__ __launch_bounds__(1024) void k_scan(const int* __restrict__ ncnt,
                                               float* invN, int* off, float* scal) {
    __shared__ int s[1024];
    __shared__ int esh;
    int tid = threadIdx.x;
    if (tid == 0) esh = 0;
    int n = (tid < CCLS) ? ncnt[tid] : 0;
    __syncthreads();
    unsigned long long m = __ballot(n > 0);
    if ((tid & 63) == 0) atomicAdd(&esh, __popcll(m));
    if (tid < CCLS) invN[tid] = (n > 0) ? 1.0f / (float)n : 0.f;
    int v = (tid < CCLS) ? (n + 1) : 0;
    s[tid] = v;
    __syncthreads();
    for (int d = 1; d < 1024; d <<= 1) {
        int add = (tid >= d) ? s[tid - d] : 0;
        __syncthreads();
        s[tid] += add;
        __syncthreads();
    }
    if (tid < CCLS) off[tid] = s[tid] - v;
    if (tid == CCLS - 1) off[CCLS] = s[tid];
    if (tid == 0) scal[0] = (float)esh;
}

__global__ void k_scatter(const float* __restrict__ pred, const int* __restrict__ target,
                          const int* __restrict__ off, int* fill, float* thr_g, int B) {
    int j = blockIdx.x * 256 + threadIdx.x;
    if (j >= B) return;
    int tj = target[j];
    float fo = pred[(size_t)j * CCLS + tj];
    int pos = off[tj] + atomicAdd(&fill[tj], 1);
    thr_g[pos] = fo - 1.0f;
}

// wave-per-class rank sort + prefix via shuffles (cnt<=64 fast path; serial fallback for safety)
__global__ __launch_bounds__(256) void k_sortpfx(const int* __restrict__ ncnt,
                                                 const int* __restrict__ off,
                                                 float* thr_g, float* pref_g) {
    int wid = (blockIdx.x * 256 + threadIdx.x) >> 6;  // global wave id = class
    int lane = threadIdx.x & 63;
    if (wid >= CCLS) return;
    int base = off[wid], cnt = ncnt[wid];
    if (cnt <= 64) {
        float v = (lane < cnt) ? thr_g[base + lane] : FLT_MAX;
        int rank = 0;
        float psum = 0.f, tot = 0.f;
        for (int k = 0; k < cnt; ++k) {
            float u = __shfl(v, k);
            bool sm = (u < v) || (u == v && k < lane);
            rank += sm ? 1 : 0;
            psum += sm ? u : 0.f;
            tot += u;
        }
        if (lane < cnt) { thr_g[base + rank] = v; pref_g[base + rank] = psum; }
        if (lane == 0) { thr_g[base + cnt] = FLT_MAX; pref_g[base + cnt] = tot; }
    } else if (lane == 0) {
        // correctness-only fallback (counts this large don't occur for B=12288,C=1000)
        for (int a = 1; a < cnt; ++a) {
            float v = thr_g[base + a];
            int b = a - 1;
            while (b >= 0 && thr_g[base + b] > v) { thr_g[base + b + 1] = thr_g[base + b]; --b; }
            thr_g[base + b + 1] = v;
        }
        float run = 0.f;
        for (int k = 0; k < cnt; ++k) { pref_g[base + k] = run; run += thr_g[base + k]; }
        thr_g[base + cnt] = FLT_MAX;
        pref_g[base + cnt] = run;
    }
}

__global__ __launch_bounds__(TPB) void k_main(const float* __restrict__ pred,
        const int* __restrict__ target,
        const float* __restrict__ thr_g, const float* __restrict__ pref_g,
        const int* __restrict__ off_g, const float* __restrict__ invN_g,
        float* scal, int B, int RPB) {
    __shared__ float thrL[CAP];
    __shared__ float prefL[CAP];
    __shared__ int offL[CCLS + 1];
    __shared__ float invNL[CCLS];
    __shared__ float redL[TPB / 64];

    const int tid = threadIdx.x;
    const int cchunk = blockIdx.x >> 7;          // 0..3
    const int rblk = blockIdx.x & (NRBLK - 1);   // 0..127
    const int c0 = cchunk * CCH;
    const int c1 = min(c0 + CCH, CCLS);
    const int rbase = rblk * RPB;

    for (int k = tid; k <= CCLS; k += TPB) offL[k] = off_g[k];
    for (int k = tid; k < CCLS; k += TPB) invNL[k] = invN_g[k];
    __syncthreads();
    const int sbase = offL[c0];
    const int nsl = offL[c1] - sbase;
    const bool fits = (nsl <= CAP);
    if (fits) {
        for (int k = tid; k < nsl; k += TPB) {
            thrL[k] = thr_g[sbase + k];
            prefL[k] = pref_g[sbase + k];
        }
    }
    __syncthreads();

    const int rr = tid >> 8;          // 0..3: row within 4-row group
    const int cc = tid & (CCH - 1);   // class within chunk
    const int c = c0 + cc;
    const bool cvalid = (c < c1);
    const int cload = cvalid ? c : c0;
    const float invc = cvalid ? invNL[c] : 0.f;
    const int segb = cvalid ? (offL[c] - sbase) : 0;
    const int cnt = cvalid ? (offL[c + 1] - offL[c] - 1) : 0;

    auto body = [&](const auto* thrP, const auto* prefP) -> float {
        // class is loop-invariant per thread: preload 3 binary-search levels into registers.
        const int m1 = cnt >> 1;
        const int m2A = (m1 + 1 + cnt) >> 1, m2B = m1 >> 1;
        const int i3AA = (m2A + 1 + cnt) >> 1, i3AB = (m1 + 1 + m2A) >> 1;
        const int i3BA = (m2B + 1 + m1) >> 1,  i3BB = m2B >> 1;
        const float t1  = thrP[segb + m1];
        const float t2A = thrP[segb + m2A], t2B = thrP[segb + m2B];
        const float t3AA = thrP[segb + i3AA], t3AB = thrP[segb + i3AB];
        const float t3BA = thrP[segb + i3BA], t3BB = thrP[segb + i3BB];

        float acc = 0.f;
        for (int it = 0; it * 4 + rr < RPB; ++it) {
            const int i = rbase + it * 4 + rr;
            if (i >= B) break;
            const int ti = target[i];
            const float p = pred[(size_t)i * CCLS + cload];

            bool b1 = t1 < p;
            int lo = b1 ? m1 + 1 : 0;
            int hi = b1 ? cnt : m1;
            float t2  = b1 ? t2A : t2B;
            float t3h = b1 ? t3AA : t3BA;
            float t3l = b1 ? t3AB : t3BB;

            bool b2 = t2 < p;
            int m2 = (lo + hi) >> 1;
            lo = b2 ? m2 + 1 : lo;
            hi = b2 ? hi : m2;
            float t3 = b2 ? t3h : t3l;

            bool b3 = t3 < p;
            int m3 = (lo + hi) >> 1;
            lo = b3 ? m3 + 1 : lo;
            hi = b3 ? hi : m3;

            while (lo < hi) {
                int mid = (lo + hi) >> 1;
                bool bt = thrP[segb + mid] < p;
                lo = bt ? mid + 1 : lo;
                hi = bt ? hi : mid;
            }
            float contrib = (float)lo * p - prefP[segb + lo];
            float w = (c != ti) ? invc * invNL[ti] : 0.f;
            acc = fmaf(contrib, w, acc);
        }
        return acc;
    };

    float acc = fits ? body((const float*)thrL, (const float*)prefL)
                     : body(thr_g + sbase, pref_g + sbase);

    for (int o = 32; o; o >>= 1) acc += __shfl_down(acc, o);
    if ((tid & 63) == 0) redL[tid >> 6] = acc;
    __syncthreads();
    if (tid == 0) {
        float ssum = 0.f;
        for (int k = 0; k < TPB / 64; ++k) ssum += redL[k];
        atomicAdd(&scal[1], ssum);
    }
}

__global__ void k_final(const float* __restrict__ scal, float* __restrict__ out) {
    float E = scal[0];
    out[0] = scal[1] / (E * (E - 1.0f));
}

extern "C" void kernel_launch(void* const* d_in, const int* in_sizes, int n_in,
                              void* d_out, int out_size, void* d_ws, size_t ws_size,
                              hipStream_t stream) {
    const float* pred = (const float*)d_in[0];
    const int* target = (const int*)d_in[1];
    const int B = in_sizes[1];  // 12288

    char* ws = (char*)d_ws;
    int* ncnt   = (int*)(ws + 0);        // 1024 ints
    int* fill   = (int*)(ws + 4096);     // 1024 ints
    int* off    = (int*)(ws + 8192);     // 1001 ints
    float* invN = (float*)(ws + 16384);  // 1000 floats
    float* scal = (float*)(ws + 20480);  // [0]=E, [1]=acc
    size_t slotBytes = (size_t)(B + CCLS + 64) * sizeof(float);
    float* thr_g  = (float*)(ws + 24576);
    float* pref_g = (float*)(ws + 24576 + slotBytes);

    const int gb = (B + 255) / 256;
    const int RPB = (B + NRBLK - 1) / NRBLK;

    k_init<<<4, 256, 0, stream>>>(ncnt, fill, scal);
    k_hist<<<gb, 256, 0, stream>>>(target, ncnt, B);
    k_scan<<<1, 1024, 0, stream>>>(ncnt, invN, off, scal);
    k_scatter<<<gb, 256, 0, stream>>>(pred, target, off, fill, thr_g, B);
    k_sortpfx<<<(CCLS * 64 + 255) / 256, 256, 0, stream>>>(ncnt, off, thr_g, pref_g);
    k_main<<<NCCHUNK * NRBLK, TPB, 0, stream>>>(pred, target, thr_g, pref_g, off, invN, scal, B, RPB);
    k_final<<<1, 1, 0, stream>>>(scal, (float*)d_out);
}

// Round 4
// 48.859 us; speedup vs baseline: 4.0416x; 1.0604x over previous
//
#include <hip/hip_runtime.h>
#include <float.h>

// loss = (1/(E(E-1))) * sum_{i,j: t_i != t_j} relu(pred[i,t_j] - (f_own[j]-1)) / (N[t_i] N[t_j])
// Per class c (sorted thresholds + prefix sums): row i contribution from class c is
//   k*p - prefix[k], k = #{thr < p}, p = pred[i,c].  O(B*C) items, ~5-level fixed search each.
// Padded layout: each class owns PAD=64 global slots (sorted + FLT_MAX pad), LSLOT=32 staged in LDS.

#define CCLS 1000
#define PAD 64      // global slots per class (supports class count <= 63)
#define LSLOT 32    // LDS slots per class (fast path: count <= 31; else global fallback)
#define TPB 1024
#define CCH 250     // classes per chunk -> 4 chunks
#define NCH 4
#define NRBLK 128   // row blocks per chunk
#define LSTR 257    // LDS row stride: bank = (k + cc) & 31 -> <=2-way on all accesses

__global__ __launch_bounds__(1024) void k_prep(const int* __restrict__ target, int B,
        int* ncnt, float* invN, int* fill, float* scal, int* flags) {
    __shared__ int h[CCLS];
    __shared__ int esh, mx;
    int tid = threadIdx.x;
    if (tid < CCLS) h[tid] = 0;
    if (tid == 0) { esh = 0; mx = 0; }
    __syncthreads();
    for (int j = tid; j < B; j += TPB) atomicAdd(&h[target[j]], 1);
    __syncthreads();
    if (tid < CCLS) {
        int n = h[tid];
        ncnt[tid] = n;
        invN[tid] = n ? 1.0f / (float)n : 0.f;
        fill[tid] = 0;
        if (n) atomicAdd(&esh, 1);
        atomicMax(&mx, n);
    }
    __syncthreads();
    if (tid == 0) {
        scal[0] = (float)esh;   // E
        scal[1] = 0.f;          // accumulator
        flags[0] = 0;           // k_main completion counter
        flags[1] = (mx > LSLOT - 1) ? 1 : 0;  // overflow -> global fallback path
    }
}

__global__ void k_scatter(const float* __restrict__ pred, const int* __restrict__ target,
                          int* fill, float* thrP, int B) {
    int j = blockIdx.x * 256 + threadIdx.x;
    if (j >= B) return;
    int tj = target[j];
    float fo = pred[(size_t)j * CCLS + tj];  // f_own[j]
    int pos = atomicAdd(&fill[tj], 1);
    if (pos < PAD) thrP[tj * PAD + pos] = fo - 1.0f;
}

// wave-per-class rank sort + prefix via shuffles; writes all PAD slots (FLT_MAX pad, pref[cnt]=total)
__global__ __launch_bounds__(256) void k_sortpfx(const int* __restrict__ ncnt,
                                                 float* thrP, float* prefP) {
    int c = (blockIdx.x * 256 + threadIdx.x) >> 6;
    int lane = threadIdx.x & 63;
    if (c >= CCLS) return;
    int cnt = min(ncnt[c], PAD - 1);
    int base = c * PAD;
    float v = (lane < cnt) ? thrP[base + lane] : FLT_MAX;
    int rank = 0;
    float psum = 0.f, tot = 0.f;
    for (int k = 0; k < cnt; ++k) {
        float u = __shfl(v, k);
        bool sm = (u < v) || (u == v && k < lane);
        rank += sm ? 1 : 0;
        psum += sm ? u : 0.f;
        tot += u;
    }
    if (lane < cnt) { thrP[base + rank] = v; prefP[base + rank] = psum; }
    else           { thrP[base + lane] = FLT_MAX; prefP[base + lane] = tot; }
}

__global__ __launch_bounds__(TPB) void k_main(const float* __restrict__ pred,
        const int* __restrict__ target,
        const float* __restrict__ thrP, const float* __restrict__ prefP,
        const float* __restrict__ invN,
        float* scal, int* flags, float* __restrict__ out, int B, int RPB) {
    __shared__ float thrL[LSLOT][LSTR];
    __shared__ float prefL[LSLOT][LSTR];
    __shared__ float invNL[CCLS];
    __shared__ float redL[TPB / 64];

    const int tid = threadIdx.x;
    const int chunk = blockIdx.x / NRBLK;
    const int rblk = blockIdx.x % NRBLK;
    const int c0 = chunk * CCH;
    const int rbase = rblk * RPB;
    const int ovf = flags[1];

    for (int k = tid; k < CCLS; k += TPB) invNL[k] = invN[k];
    // stage transposed [k][cc]: coalesced global reads, conflict-free LDS writes (bank=(k+cc)&31)
    for (int g = tid; g < CCH * LSLOT; g += TPB) {
        int cc = g >> 5, k = g & 31;
        thrL[k][cc] = thrP[(size_t)(c0 + cc) * PAD + k];
        prefL[k][cc] = prefP[(size_t)(c0 + cc) * PAD + k];
    }
    __syncthreads();

    const int rr = tid >> 8;        // 0..3
    const int cc = tid & 255;       // class within chunk
    const bool cvalid = cc < CCH;
    const int c = cvalid ? (c0 + cc) : c0;
    const float invc = cvalid ? invNL[c] : 0.f;

    float acc = 0.f;
    if (cvalid) {
        if (!ovf) {
            // levels 1-3 of the fixed 32-slot search tree live in registers
            const float t15 = thrL[15][cc];
            const float t7 = thrL[7][cc], t23 = thrL[23][cc];
            const float q3 = thrL[3][cc], q11 = thrL[11][cc];
            const float q19 = thrL[19][cc], q27 = thrL[27][cc];
            for (int it = 0; it * 4 + rr < RPB; ++it) {
                const int i = rbase + it * 4 + rr;
                if (i >= B) break;
                const int ti = target[i];
                const float p = pred[(size_t)i * CCLS + c];
                bool b1 = t15 < p;
                float t2 = b1 ? t23 : t7;
                bool b2 = t2 < p;
                float t3hi = b1 ? q27 : q11;
                float t3lo = b1 ? q19 : q3;
                float t3 = b2 ? t3hi : t3lo;
                bool b3 = t3 < p;
                int lo = (b1 ? 16 : 0) + (b2 ? 8 : 0) + (b3 ? 4 : 0);
                lo += (thrL[lo + 1][cc] < p) ? 2 : 0;   // level 4
                lo += (thrL[lo][cc] < p) ? 1 : 0;       // level 5
                float contrib = (float)lo * p - prefL[lo][cc];
                float w = (c != ti) ? invc * invNL[ti] : 0.f;
                acc = fmaf(contrib, w, acc);
            }
        } else {
            // correctness fallback (class count > 31): 6-level search in global padded segment
            const float* seg = thrP + (size_t)c * PAD;
            const float* pseg = prefP + (size_t)c * PAD;
            for (int it = 0; it * 4 + rr < RPB; ++it) {
                const int i = rbase + it * 4 + rr;
                if (i >= B) break;
                const int ti = target[i];
                const float p = pred[(size_t)i * CCLS + c];
                int lo = 0;
#pragma unroll
                for (int s = 32; s; s >>= 1) lo += (seg[lo + s - 1] < p) ? s : 0;
                float contrib = (float)lo * p - pseg[lo];
                float w = (c != ti) ? invc * invNL[ti] : 0.f;
                acc = fmaf(contrib, w, acc);
            }
        }
    }

    for (int o = 32; o; o >>= 1) acc += __shfl_down(acc, o);
    if ((tid & 63) == 0) redL[tid >> 6] = acc;
    __syncthreads();
    if (tid == 0) {
        float ssum = 0.f;
#pragma unroll
        for (int k = 0; k < TPB / 64; ++k) ssum += redL[k];
        atomicAdd(&scal[1], ssum);
        __threadfence();
        int done = atomicAdd(&flags[0], 1);
        if (done == (int)gridDim.x - 1) {   // last block finalizes (fused k_final)
            float tot = atomicAdd(&scal[1], 0.f);
            float E = scal[0];
            out[0] = tot / (E * (E - 1.0f));
        }
    }
}

extern "C" void kernel_launch(void* const* d_in, const int* in_sizes, int n_in,
                              void* d_out, int out_size, void* d_ws, size_t ws_size,
                              hipStream_t stream) {
    const float* pred = (const float*)d_in[0];
    const int* target = (const int*)d_in[1];
    const int B = in_sizes[1];  // 12288

    char* ws = (char*)d_ws;
    int* ncnt    = (int*)(ws + 0);        // 1000 ints
    float* invN  = (float*)(ws + 4096);   // 1000 floats
    int* fill    = (int*)(ws + 8192);     // 1000 ints
    float* scal  = (float*)(ws + 12288);  // [0]=E, [1]=acc
    int* flags   = (int*)(ws + 12352);    // [0]=counter, [1]=overflow
    float* thrP  = (float*)(ws + 16384);            // 1000*64 floats (256KB)
    float* prefP = (float*)(ws + 16384 + 262144);   // 1000*64 floats (256KB)

    const int gb = (B + 255) / 256;
    const int RPB = (B + NRBLK - 1) / NRBLK;

    k_prep<<<1, TPB, 0, stream>>>(target, B, ncnt, invN, fill, scal, flags);
    k_scatter<<<gb, 256, 0, stream>>>(pred, target, fill, thrP, B);
    k_sortpfx<<<(CCLS * 64 + 255) / 256, 256, 0, stream>>>(ncnt, thrP, prefP);
    k_main<<<NCH * NRBLK, TPB, 0, stream>>>(pred, target, thrP, prefP, invN,
                                            scal, flags, (float*)d_out, B, RPB);
}